// Round 9
// baseline (358.430 us; speedup 1.0000x reference)
//
#include <hip/hip_runtime.h>
#include <math.h>

#ifndef M_PI
#define M_PI 3.14159265358979323846
#endif

// ---------------- constants ----------------
#define NSIDE 128
#define NVOX  2097152          // 128^3
#define KBINS 100
#define NFIELDS 16             // 8 pred + 8 target
#define NORMF (27.0f / 2097152.0f)   // LPIX^3 / N^3
#define FSTRIDE ((size_t)65 * 16384) // float2 elems per field (kz-major planes)

// ws layout (bytes)
#define WS_SUMS_OFF   0                       // float[16*101]
#define WS_CNT_OFF    6464                    // int[101]
#define WS_OCT_OFF    8192                    // uint8[65*65*65], kz-major: oct[c][a][b]
#define WS_TRANS_OFF  282880                  // float2[16 * FSTRIDE] = 136.3 MB

// ---------------- exact numpy binning replication (fp64) ----------------
__device__ __forceinline__ double bin_edge(int i, double start, double step, double stop) {
    if (i == 100) return stop;
    return __dadd_rn(__dmul_rn((double)i, step), start);
}

__device__ __forceinline__ void bin_params(double* start, double* step, double* stop) {
    const double inv   = 1.0 / 384.0;
    const double twopi = 2.0 * M_PI;
    double k1 = __dmul_rn(twopi, __dmul_rn(1.0, inv));
    *start = sqrt(__dadd_rn(__dadd_rn(0.0, 0.0), __dmul_rn(k1, k1)));
    double k64 = __dmul_rn(twopi, __dmul_rn(-64.0, inv));
    double s64 = __dmul_rn(k64, k64);
    *stop = sqrt(__dadd_rn(__dadd_rn(s64, s64), s64));
    *step = (*stop - *start) / 100.0;
}

__device__ int compute_bin(int ix, int iy, int iz) {
    const double inv   = 1.0 / 384.0;
    const double twopi = 2.0 * M_PI;
    double fx = (double)(ix < 64 ? ix : ix - 128);
    double fy = (double)(iy < 64 ? iy : iy - 128);
    double fz = (double)(iz < 64 ? iz : iz - 128);
    double kx = __dmul_rn(twopi, __dmul_rn(fx, inv));
    double ky = __dmul_rn(twopi, __dmul_rn(fy, inv));
    double kz = __dmul_rn(twopi, __dmul_rn(fz, inv));
    double sq = __dadd_rn(__dadd_rn(__dmul_rn(kx, kx), __dmul_rn(ky, ky)), __dmul_rn(kz, kz));
    double kmag = sqrt(sq);
    if (!(kmag > 0.0)) return 100;                   // DC -> dropped bin
    double start, step, stop;
    bin_params(&start, &step, &stop);
    double t = (kmag - start) / step;
    int c = (int)floor(t);
    if (c < -1) c = -1;
    if (c > 100) c = 100;
    while (c < 100 && kmag >= bin_edge(c + 1, start, step, stop)) ++c;
    while (c >= 0 && kmag < bin_edge(c, start, step, stop)) --c;
    if (c < 0) c = 0;
    if (c > 99) c = 99;
    return c;
}

// ---------------- R=16 register-resident 128-pt FFT ----------------
// 8 lanes per line; lane m (=lane&7) holds elements n = m + 8j in r[j], j=0..15.
// Radix-2 DIF: strides 64/32/16/8 in-register, strides 4/2/1 via shfl_xor.
// In-place: position n = m+8j ends holding X[bitrev7(n)],
// i.e. frequency k = (br3(m)<<4) | br4(j).

__device__ __forceinline__ int br3(int v) { return ((v & 1) << 2) | (v & 2) | ((v >> 2) & 1); }
__device__ __forceinline__ int br4(int v) {
    return ((v & 1) << 3) | ((v & 2) << 1) | ((v & 4) >> 1) | ((v & 8) >> 3);
}

__device__ __forceinline__ float2 f2add(float2 a, float2 b) { return make_float2(a.x + b.x, a.y + b.y); }
__device__ __forceinline__ float2 f2sub(float2 a, float2 b) { return make_float2(a.x - b.x, a.y - b.y); }
__device__ __forceinline__ float2 cmul(float2 a, float2 w) {
    return make_float2(a.x * w.x - a.y * w.y, a.x * w.y + a.y * w.x);
}
__device__ __forceinline__ float2 twid(float r) {   // e^{2*pi*i*r}, r in revolutions
    return make_float2(__builtin_amdgcn_cosf(r), __builtin_amdgcn_sinf(r));
}

__device__ __forceinline__ void fft128_r16(float2 r[16], int m) {
    const float fm = (float)m;
    // h=64: pairs (j, j+8); twiddle -(m+8j)/128
#pragma unroll
    for (int j = 0; j < 8; ++j) {
        float2 W = twid(-(fm + 8.0f * (float)j) * (1.0f / 128.0f));
        float2 a = r[j], b = r[j + 8];
        r[j]     = f2add(a, b);
        r[j + 8] = cmul(f2sub(a, b), W);
    }
    // h=32: pairs (j, j+4) per half; twiddle -(m+8*(j&3))/64
#pragma unroll
    for (int j = 0; j < 4; ++j) {
        float2 W = twid(-(fm + 8.0f * (float)j) * (1.0f / 64.0f));
#pragma unroll
        for (int half = 0; half < 16; half += 8) {
            float2 a = r[half + j], b = r[half + j + 4];
            r[half + j]     = f2add(a, b);
            r[half + j + 4] = cmul(f2sub(a, b), W);
        }
    }
    // h=16: pairs (j, j+2) per quarter; twiddle -(m+8*(j&1))/32
#pragma unroll
    for (int j = 0; j < 2; ++j) {
        float2 W = twid(-(fm + 8.0f * (float)j) * (1.0f / 32.0f));
#pragma unroll
        for (int q = 0; q < 16; q += 4) {
            float2 a = r[q + j], b = r[q + j + 2];
            r[q + j]     = f2add(a, b);
            r[q + j + 2] = cmul(f2sub(a, b), W);
        }
    }
    // h=8: pairs (j, j+1); twiddle -m/16
    {
        float2 W = twid(-fm * (1.0f / 16.0f));
#pragma unroll
        for (int q = 0; q < 16; q += 2) {
            float2 a = r[q], b = r[q + 1];
            r[q]     = f2add(a, b);
            r[q + 1] = cmul(f2sub(a, b), W);
        }
    }
    // cross-lane h=4,2 (stays within the 8-lane line group)
#pragma unroll
    for (int h = 4; h >= 2; h >>= 1) {
        bool hi = (m & h) != 0;
        float2 W = twid(-(float)(m & (h - 1)) / (float)(2 * h));
#pragma unroll
        for (int j = 0; j < 16; ++j) {
            float2 x = r[j];
            float2 v = make_float2(__shfl_xor(x.x, h, 64), __shfl_xor(x.y, h, 64));
            float2 s = f2add(x, v);
            float2 d = cmul(f2sub(v, x), W);
            r[j] = hi ? d : s;
        }
    }
    // h=1: no twiddle
    {
        bool hi = (m & 1) != 0;
#pragma unroll
        for (int j = 0; j < 16; ++j) {
            float2 x = r[j];
            float2 v = make_float2(__shfl_xor(x.x, 1, 64), __shfl_xor(x.y, 1, 64));
            r[j] = hi ? f2sub(v, x) : f2add(x, v);
        }
    }
}

// ---------------- kernels ----------------
__global__ __launch_bounds__(256) void k_zero(float* sums, int* counts) {
    int t = blockIdx.x * 256 + threadIdx.x;
    if (t < NFIELDS * 101) sums[t] = 0.0f;
    if (t < 101) counts[t] = 0;
}

// Octant bin table (kz-major: oct[c][a][b]) + exact weighted mode counts.
__global__ __launch_bounds__(256) void k_oct(unsigned char* __restrict__ oct,
                                             int* __restrict__ counts) {
    __shared__ int lcnt[4][104];
    int tid = threadIdx.x;
#pragma unroll
    for (int j = tid; j < 4 * 104; j += 256) ((int*)lcnt)[j] = 0;
    __syncthreads();
    int idx = blockIdx.x * 256 + tid;
    if (idx < 65 * 65 * 65) {
        int c = idx % 65;
        int r = idx / 65;
        int b = r % 65;
        int a = r / 65;
        int id = compute_bin(a, b, c);
        oct[c * 4225 + a * 65 + b] = (unsigned char)id;
        if (id < 100) {
            int w = ((a == 0 || a == 64) ? 1 : 2) *
                    ((b == 0 || b == 64) ? 1 : 2) *
                    ((c == 0 || c == 64) ? 1 : 2);
            atomicAdd(&lcnt[tid & 3][id], w);
        }
    }
    __syncthreads();
    if (tid < 101) {
        int tot = lcnt[0][tid] + lcnt[1][tid] + lcnt[2][tid] + lcnt[3][tid];
        if (tot) atomicAdd(&counts[tid], tot);
    }
}

// Pass Z: FFT along z in registers. Block: 256 thr = 32 z-lines (fixed x,
// 32 consecutive y). No LDS; kz<=64 decimation in the store pattern.
__global__ __launch_bounds__(256) void k_fft_z(const float* __restrict__ pred,
                                               const float* __restrict__ target,
                                               float2* __restrict__ A) {
    int t = threadIdx.x;
    int m = t & 7, row = t >> 3;          // 32 rows (y)
    int x  = blockIdx.x >> 2;
    int y0 = (blockIdx.x & 3) << 5;
    int f = blockIdx.y;
    const float* in = (f < 8) ? (pred + (size_t)f * NVOX)
                              : (target + (size_t)(f - 8) * NVOX);
    const float* src = in + (size_t)x * 16384 + (size_t)(y0 + row) * 128;
    float2 r[16];
#pragma unroll
    for (int j = 0; j < 16; ++j) r[j] = make_float2(src[m + 8 * j], 0.0f);
    fft128_r16(r, m);
    float2* dst = A + (size_t)f * FSTRIDE + (size_t)x * 128 + (y0 + row);
    int b3 = br3(m);                       // kz = 16*b3 + br4(j)
    if (b3 < 4) {
#pragma unroll
        for (int j = 0; j < 16; ++j) {
            int kz = 16 * b3 + br4(j);
            dst[(size_t)kz * 16384] = r[j];
        }
    } else if (b3 == 4) {                  // m==1: only j=0 -> kz=64
        dst[(size_t)64 * 16384] = r[0];
    }
}

// Fused pass Y+X: one (kz, field) plane per block. 1024 threads.
// y-FFT in regs (contiguous plane read) -> LDS transpose (one round trip,
// 2 barriers total) -> x-FFT in regs -> power + radial binning from regs.
__global__ __launch_bounds__(1024) void k_plane2(const float2* __restrict__ A,
                                                 const unsigned char* __restrict__ oct,
                                                 float* __restrict__ sums) {
    __shared__ float2 P[128][130];        // [x][y-slot], pad 130 vs 128
    __shared__ float lbins[8][104];
    __shared__ unsigned char ltab[4225];
    int t = threadIdx.x;
    int kz = blockIdx.x, f = blockIdx.y;
    const float2* plane = A + (size_t)f * FSTRIDE + (size_t)kz * 16384;
    for (int j = t; j < 8 * 104; j += 1024) ((float*)lbins)[j] = 0.0f;
    for (int j = t; j < 4225; j += 1024) ltab[j] = oct[kz * 4225 + j];
    int m = t & 7, g = t >> 3;            // y-phase: g = x row (0..127)
    float2 r[16];
    const float2* rowp = plane + (size_t)g * 128;
#pragma unroll
    for (int j = 0; j < 16; ++j) r[j] = rowp[m + 8 * j];
    fft128_r16(r, m);                     // y-FFT of row g
#pragma unroll
    for (int j = 0; j < 16; ++j) P[g][m + 8 * j] = r[j];   // y in slot order
    __syncthreads();
    // x-phase: thread (m, g) where g = y-slot (0..127); read column m+8j
#pragma unroll
    for (int j = 0; j < 16; ++j) r[j] = P[m + 8 * j][g];
    fft128_r16(r, m);                     // x-FFT
    int ky = (br3(g & 7) << 4) | br4(g >> 3);
    int mky = (ky <= 64) ? ky : 128 - ky;
    int b3x = br3(m) << 4;
#pragma unroll
    for (int j = 0; j < 16; ++j) {
        int kx = b3x | br4(j);
        int mkx = (kx <= 64) ? kx : 128 - kx;
        float pk = r[j].x * r[j].x + r[j].y * r[j].y;
        atomicAdd(&lbins[t & 7][ltab[mkx * 65 + mky]], pk);
    }
    __syncthreads();
    if (t < 101) {
        float wz = (kz == 0 || kz == 64) ? 1.0f : 2.0f;
        float v = lbins[0][t] + lbins[1][t] + lbins[2][t] + lbins[3][t] +
                  lbins[4][t] + lbins[5][t] + lbins[6][t] + lbins[7][t];
        if (v != 0.0f) atomicAdd(&sums[f * 101 + t], v * (NORMF) * wz);
    }
}

// Finalize: Delta^2, log10 ratio, nanmean -> scalar.
__global__ __launch_bounds__(128) void k_finalize(const float* __restrict__ sums,
                                                  const int* __restrict__ counts,
                                                  float* __restrict__ out) {
    __shared__ double ssum[128];
    __shared__ int scnt[128];
    int k = threadIdx.x;
    double local = 0.0;
    int nloc = 0;
    if (k < KBINS) {
        int c = counts[k];
        if (c > 0) {
            double start, step, stop;
            bin_params(&start, &step, &stop);
            double e0 = bin_edge(k, start, step, stop);
            double e1 = bin_edge(k + 1, start, step, stop);
            float kc  = (float)(0.5 * (e0 + e1));
            float kc3 = kc * kc * kc;
            const float two_pi2 = (float)(2.0 * M_PI * M_PI);
            float cf = (float)c;
            for (int b = 0; b < 8; ++b) {
                float pm_p = sums[b * 101 + k] / cf;
                float pm_t = sums[(8 + b) * 101 + k] / cf;
                float dsq_p = pm_p * kc3 / two_pi2;
                float dsq_t = pm_t * kc3 / two_pi2;
                float d = fabsf(log10f(dsq_t) - log10f(dsq_p));
                local += (double)d;
            }
            nloc = 8;
        }
    }
    ssum[k] = local;
    scnt[k] = nloc;
    __syncthreads();
    for (int off = 64; off > 0; off >>= 1) {
        if (k < off) { ssum[k] += ssum[k + off]; scnt[k] += scnt[k + off]; }
        __syncthreads();
    }
    if (k == 0) out[0] = (float)(ssum[0] / (double)scnt[0]);
}

// ---------------- launch ----------------
extern "C" void kernel_launch(void* const* d_in, const int* in_sizes, int n_in,
                              void* d_out, int out_size, void* d_ws, size_t ws_size,
                              hipStream_t stream) {
    (void)in_sizes; (void)n_in; (void)out_size; (void)ws_size;
    const float* pred   = (const float*)d_in[0];
    const float* target = (const float*)d_in[1];
    float* out = (float*)d_out;
    char* ws = (char*)d_ws;

    float* sums        = (float*)(ws + WS_SUMS_OFF);   // [16][101]
    int* counts        = (int*)(ws + WS_CNT_OFF);      // [101]
    unsigned char* oct = (unsigned char*)(ws + WS_OCT_OFF);
    float2* A          = (float2*)(ws + WS_TRANS_OFF); // [65][128][128] per field

    k_zero<<<7, 256, 0, stream>>>(sums, counts);
    k_oct<<<(65 * 65 * 65 + 255) / 256, 256, 0, stream>>>(oct, counts);

    k_fft_z<<<dim3(512, NFIELDS), 256, 0, stream>>>(pred, target, A);
    k_plane2<<<dim3(65, NFIELDS), 1024, 0, stream>>>(A, oct, sums);

    k_finalize<<<1, 128, 0, stream>>>(sums, counts, out);
}